// Round 1
// baseline (199.049 us; speedup 1.0000x reference)
//
#include <hip/hip_runtime.h>
#include <stdint.h>

// Problem constants
constexpr int NB = 8;      // batch
constexpr int NS = 2048;   // nodes
constexpr int ND = 256;    // in dim
constexpr int NDO = 256;   // out dim
constexpr int NL = 8;      // labels
constexpr int NE = 32768;  // edges per batch

typedef __attribute__((ext_vector_type(8))) short bf16x8;
typedef __attribute__((ext_vector_type(4))) float f32x4;

__device__ __forceinline__ float bf2f(uint32_t u) {
    return __uint_as_float(u << 16);
}
__device__ __forceinline__ uint16_t f2bf(float f) {
    uint32_t x = __float_as_uint(f);
    uint32_t r = (x + 0x7fffu + ((x >> 16) & 1u)) >> 16;
    return (uint16_t)r;
}

// ---- convert node_repr f32 -> bf16 (4 elems/thread) ----
__global__ void convert_x_kernel(const float* __restrict__ x, ushort* __restrict__ xb) {
    int i = blockIdx.x * blockDim.x + threadIdx.x;   // < NB*NS*ND/4
    const float4* xv = (const float4*)x;
    float4 v = xv[i];
    ushort4 o;
    o.x = f2bf(v.x); o.y = f2bf(v.y); o.z = f2bf(v.z); o.w = f2bf(v.w);
    ((ushort4*)xb)[i] = o;
}

// ---- transpose+convert W[l][d][o] -> Wt[l][o][d] bf16 ----
__global__ void convert_wt_kernel(const float* __restrict__ W, ushort* __restrict__ wt) {
    int i = blockIdx.x * blockDim.x + threadIdx.x;   // < NL*NDO*ND
    int d = i & (ND - 1);
    int o = (i >> 8) & (NDO - 1);
    int l = i >> 16;
    wt[i] = f2bf(W[(size_t)(l * ND + d) * NDO + o]);
}

// ---- histogram of edge targets ----
__global__ void hist_kernel(const int* __restrict__ tgt, int* __restrict__ counts) {
    int i = blockIdx.x * blockDim.x + threadIdx.x;   // < NB*NE
    int b = i >> 15;                                  // NE = 32768
    atomicAdd(&counts[b * NS + tgt[i]], 1);
}

// ---- per-batch exclusive scan over S=2048 counters (1 block/batch) ----
__global__ void scan_kernel(const int* __restrict__ counts,
                            int* __restrict__ offsets, int* __restrict__ cursor) {
    int b = blockIdx.x;
    int t = threadIdx.x;  // 256 threads, 8 counters each
    __shared__ int part[256];
    int base = b * NS + t * 8;
    int s = 0;
    for (int i = 0; i < 8; i++) s += counts[base + i];
    part[t] = s;
    __syncthreads();
    if (t == 0) {
        int run = 0;
        for (int i = 0; i < 256; i++) { int v = part[i]; part[i] = run; run += v; }
    }
    __syncthreads();
    int run = part[t];
    for (int i = 0; i < 8; i++) {
        offsets[base + i] = run;
        cursor[base + i] = run;
        run += counts[base + i];
    }
}

// ---- placement: counting-sort edge ids by target ----
__global__ void place_kernel(const int* __restrict__ tgt, int* __restrict__ cursor,
                             int* __restrict__ sorted) {
    int i = blockIdx.x * blockDim.x + threadIdx.x;   // < NB*NE
    int b = i >> 15;
    int e = i & (NE - 1);
    int p = atomicAdd(&cursor[b * NS + tgt[i]], 1);
    sorted[b * NE + p] = e;
}

// ---- per-label transform: y[b][l][s][o] = x[b][s]@W[l] + bias[l], bf16 out ----
// 128x128 block tile, 4 waves in 2x2, each wave 4x4 MFMA 16x16x32 subtiles.
__global__ __launch_bounds__(256) void gemm_kernel(
    const ushort* __restrict__ xb, const ushort* __restrict__ wt,
    const float* __restrict__ bias, ushort* __restrict__ y) {
    int n0 = blockIdx.x * 128;                 // DO tile (2)
    int m0 = blockIdx.y * 128;                 // S tile (16)
    int bl = blockIdx.z;                       // b*L + l (64)
    int b = bl >> 3;
    int l = bl & 7;

    __shared__ ushort As[128 * 40];            // padded stride 40 (2-way bank alias only)
    __shared__ ushort Bs[128 * 40];

    int tid = threadIdx.x;
    int lane = tid & 63;
    int wid = tid >> 6;
    int wm = wid & 1, wn = wid >> 1;
    int ln = lane & 15, quad = lane >> 4;

    f32x4 acc[4][4] = {};

    const ushort* Ag = xb + (size_t)(b * NS + m0) * ND;
    const ushort* Bg = wt + (size_t)(l * NDO + n0) * ND;

    for (int k0 = 0; k0 < ND; k0 += 32) {
        // stage 128 rows x 32 cols of A and Bt (each thread: 2x 16B chunks per matrix)
        for (int it = 0; it < 2; it++) {
            int idx = it * 256 + tid;
            int r = idx >> 2;
            int c = (idx & 3) << 3;
            *(uint4*)&As[r * 40 + c] = *(const uint4*)&Ag[(size_t)r * ND + k0 + c];
            *(uint4*)&Bs[r * 40 + c] = *(const uint4*)&Bg[(size_t)r * ND + k0 + c];
        }
        __syncthreads();

        bf16x8 af[4], bfr[4];
        for (int i = 0; i < 4; i++)
            af[i] = *(const bf16x8*)&As[(wm * 64 + i * 16 + ln) * 40 + quad * 8];
        for (int j = 0; j < 4; j++)
            bfr[j] = *(const bf16x8*)&Bs[(wn * 64 + j * 16 + ln) * 40 + quad * 8];
        for (int i = 0; i < 4; i++)
            for (int j = 0; j < 4; j++)
                acc[i][j] = __builtin_amdgcn_mfma_f32_16x16x32_bf16(af[i], bfr[j], acc[i][j], 0, 0, 0);
        __syncthreads();
    }

    // epilogue: C/D layout col=lane&15, row=quad*4+r
    ushort* yb = y + (size_t)(b * NL + l) * NS * NDO;
    for (int j = 0; j < 4; j++) {
        int col = n0 + wn * 64 + j * 16 + ln;
        float bv = bias[l * NDO + col];
        for (int i = 0; i < 4; i++) {
            int rbase = m0 + wm * 64 + i * 16 + quad * 4;
            for (int r = 0; r < 4; r++) {
                yb[(size_t)(rbase + r) * NDO + col] = f2bf(acc[i][j][r] + bv);
            }
        }
    }
}

// ---- gather: one wave per (b,t); sum incoming messages; fused relu ----
__global__ __launch_bounds__(256) void gather_kernel(
    const ushort* __restrict__ y,
    const int* __restrict__ esrc, const int* __restrict__ elab,
    const int* __restrict__ counts, const int* __restrict__ offsets,
    const int* __restrict__ sorted, float* __restrict__ out) {
    int g = blockIdx.x * 4 + (threadIdx.x >> 6);     // (b,t) id, < NB*NS
    int lane = threadIdx.x & 63;
    int b = g >> 11;                                  // NS = 2048
    int t = g & (NS - 1);

    int n = counts[b * NS + t];
    int off = offsets[b * NS + t];
    const int* elist = sorted + (size_t)b * NE + off;
    const int* labs = elab + (size_t)b * NE;
    const int* srcs = esrc + (size_t)b * NE;

    float ax = 0.f, ay = 0.f, az = 0.f, aw = 0.f;
    for (int k = 0; k < n; k++) {
        int e = elist[k];
        int lab = labs[e];
        int src = srcs[e];
        const uint2* row = (const uint2*)(y + ((size_t)((b * NL + lab) * NS + src)) * NDO);
        uint2 v = row[lane];                          // 4 bf16 per lane
        ax += bf2f(v.x & 0xffffu);
        ay += bf2f(v.x >> 16);
        az += bf2f(v.y & 0xffffu);
        aw += bf2f(v.y >> 16);
    }
    float4 r;
    r.x = fmaxf(ax, 0.f);
    r.y = fmaxf(ay, 0.f);
    r.z = fmaxf(az, 0.f);
    r.w = fmaxf(aw, 0.f);
    ((float4*)(out + (size_t)(b * NS + t) * NDO))[lane] = r;
}

extern "C" void kernel_launch(void* const* d_in, const int* in_sizes, int n_in,
                              void* d_out, int out_size, void* d_ws, size_t ws_size,
                              hipStream_t stream) {
    const float* x    = (const float*)d_in[0];
    const int*   esrc = (const int*)d_in[1];
    const int*   etgt = (const int*)d_in[2];
    const int*   elab = (const int*)d_in[3];
    const float* W    = (const float*)d_in[4];
    const float* bias = (const float*)d_in[5];
    float* out = (float*)d_out;

    char* ws = (char*)d_ws;
    // workspace layout (all 4KB-aligned offsets)
    ushort* xb     = (ushort*)(ws);                    //  8 MB: x bf16
    ushort* wt     = (ushort*)(ws + 8388608);          //  1 MB: W^T bf16
    ushort* y      = (ushort*)(ws + 9437184);          // 64 MB: y bf16
    int*    counts = (int*)(ws + 76546048);            // 64 KB
    int*    offs   = (int*)(ws + 76611584);            // 64 KB
    int*    cursor = (int*)(ws + 76677120);            // 64 KB
    int*    sorted = (int*)(ws + 76742656);            //  1 MB

    hipMemsetAsync(counts, 0, NB * NS * sizeof(int), stream);

    convert_x_kernel<<<4096, 256, 0, stream>>>(x, xb);          // NB*NS*ND/4/256
    convert_wt_kernel<<<2048, 256, 0, stream>>>(W, wt);         // NL*NDO*ND/256
    hist_kernel<<<1024, 256, 0, stream>>>(etgt, counts);        // NB*NE/256
    scan_kernel<<<NB, 256, 0, stream>>>(counts, offs, cursor);
    place_kernel<<<1024, 256, 0, stream>>>(etgt, cursor, sorted);
    gemm_kernel<<<dim3(2, 16, 64), 256, 0, stream>>>(xb, wt, bias, y);
    gather_kernel<<<4096, 256, 0, stream>>>(y, esrc, elab, counts, offs, sorted, out);
}

// Round 2
// 168.432 us; speedup vs baseline: 1.1818x; 1.1818x over previous
//
#include <hip/hip_runtime.h>
#include <stdint.h>

// Problem constants
constexpr int NB = 8;      // batch
constexpr int NS = 2048;   // nodes
constexpr int ND = 256;    // in dim
constexpr int NDO = 256;   // out dim
constexpr int NL = 8;      // labels
constexpr int NE = 32768;  // edges per batch

typedef __attribute__((ext_vector_type(8))) short bf16x8;
typedef __attribute__((ext_vector_type(4))) float f32x4;
typedef unsigned int u32;

__device__ __forceinline__ float bf2f(uint32_t u) {
    return __uint_as_float(u << 16);
}
__device__ __forceinline__ uint16_t f2bf(float f) {
    uint32_t x = __float_as_uint(f);
    uint32_t r = (x + 0x7fffu + ((x >> 16) & 1u)) >> 16;
    return (uint16_t)r;
}

// async global->LDS, 16B per lane; lds ptr must be wave-uniform (HW adds lane*16)
__device__ __forceinline__ void gl_lds16(const void* gptr, void* lptr) {
    __builtin_amdgcn_global_load_lds(
        (const __attribute__((address_space(1))) u32*)gptr,
        (__attribute__((address_space(3))) u32*)lptr, 16, 0, 0);
}

// ---- convert node_repr f32 -> bf16 (4 elems/thread) ----
__global__ void convert_x_kernel(const float* __restrict__ x, ushort* __restrict__ xb) {
    int i = blockIdx.x * blockDim.x + threadIdx.x;   // < NB*NS*ND/4
    const float4* xv = (const float4*)x;
    float4 v = xv[i];
    ushort4 o;
    o.x = f2bf(v.x); o.y = f2bf(v.y); o.z = f2bf(v.z); o.w = f2bf(v.w);
    ((ushort4*)xb)[i] = o;
}

// ---- transpose+convert W[l][d][o] -> Wt[l][o][d] bf16 ----
__global__ void convert_wt_kernel(const float* __restrict__ W, ushort* __restrict__ wt) {
    int i = blockIdx.x * blockDim.x + threadIdx.x;   // < NL*NDO*ND
    int d = i & (ND - 1);
    int o = (i >> 8) & (NDO - 1);
    int l = i >> 16;
    wt[i] = f2bf(W[(size_t)(l * ND + d) * NDO + o]);
}

// ---- histogram of edge targets ----
__global__ void hist_kernel(const int* __restrict__ tgt, int* __restrict__ counts) {
    int i = blockIdx.x * blockDim.x + threadIdx.x;   // < NB*NE
    int b = i >> 15;                                  // NE = 32768
    atomicAdd(&counts[b * NS + tgt[i]], 1);
}

// ---- per-batch exclusive scan over S=2048 counters (1 block/batch) ----
__global__ void scan_kernel(const int* __restrict__ counts,
                            int* __restrict__ offsets, int* __restrict__ cursor) {
    int b = blockIdx.x;
    int t = threadIdx.x;  // 256 threads, 8 counters each
    __shared__ int part[256];
    int base = b * NS + t * 8;
    int s = 0;
    for (int i = 0; i < 8; i++) s += counts[base + i];
    part[t] = s;
    __syncthreads();
    if (t == 0) {
        int run = 0;
        for (int i = 0; i < 256; i++) { int v = part[i]; part[i] = run; run += v; }
    }
    __syncthreads();
    int run = part[t];
    for (int i = 0; i < 8; i++) {
        offsets[base + i] = run;
        cursor[base + i] = run;
        run += counts[base + i];
    }
}

// ---- placement: counting-sort; store precomputed y-row index, not edge id ----
__global__ void place_kernel(const int* __restrict__ tgt,
                             const int* __restrict__ esrc, const int* __restrict__ elab,
                             int* __restrict__ cursor, int* __restrict__ sorted) {
    int i = blockIdx.x * blockDim.x + threadIdx.x;   // < NB*NE
    int b = i >> 15;
    int tg = tgt[i];
    int lab = elab[i];
    int src = esrc[i];
    int p = atomicAdd(&cursor[b * NS + tg], 1);
    sorted[b * NE + p] = (b * NL + lab) * NS + src;  // row index into y
}

// ---- per-label transform: y[b][l][s][o] = x[b][s]@W[l] + bias[l], bf16 out ----
// 128x128 block tile, 4 waves in 2x2, each wave 4x4 MFMA 16x16x32 subtiles.
// m97 staging: unpadded stride-32 LDS + global_load_lds width 16.
__global__ __launch_bounds__(256) void gemm_kernel(
    const ushort* __restrict__ xb, const ushort* __restrict__ wt,
    const float* __restrict__ bias, ushort* __restrict__ y) {
    int n0 = blockIdx.x * 128;                 // DO tile (2)
    int m0 = blockIdx.y * 128;                 // S tile (16)
    int bl = blockIdx.z;                       // b*L + l (64)
    int b = bl >> 3;
    int l = bl & 7;

    __shared__ ushort As[128 * 32];            // 8 KB, unpadded (global_load_lds needs contiguity)
    __shared__ ushort Bs[128 * 32];

    int tid = threadIdx.x;
    int lane = tid & 63;
    int wave = __builtin_amdgcn_readfirstlane(tid >> 6);
    int wm = wave & 1, wn = wave >> 1;
    int ln = lane & 15, quad = lane >> 4;

    f32x4 acc[4][4] = {};

    const ushort* Ag = xb + (size_t)(b * NS + m0) * ND;
    const ushort* Bg = wt + (size_t)(l * NDO + n0) * ND;

    // per-lane chunk coords for the two staging passes (cid = it*256 + tid)
    int r0 = tid >> 2, c0 = (tid & 3) << 3;           // it=0: cid 0..255
    int r1 = (256 + tid) >> 2, c1 = c0;               // it=1: cid 256..511

    for (int k0 = 0; k0 < ND; k0 += 32) {
        // wave-uniform LDS bases: chunk range [it*256 + wave*64, +64), 16B/lane
        ushort* lA0 = &As[(wave * 64) * 8];
        ushort* lA1 = &As[(256 + wave * 64) * 8];
        ushort* lB0 = &Bs[(wave * 64) * 8];
        ushort* lB1 = &Bs[(256 + wave * 64) * 8];
        gl_lds16(Ag + (size_t)r0 * ND + k0 + c0, lA0);
        gl_lds16(Ag + (size_t)r1 * ND + k0 + c1, lA1);
        gl_lds16(Bg + (size_t)r0 * ND + k0 + c0, lB0);
        gl_lds16(Bg + (size_t)r1 * ND + k0 + c1, lB1);
        __syncthreads();

        bf16x8 af[4], bfr[4];
        for (int i = 0; i < 4; i++)
            af[i] = *(const bf16x8*)&As[(wm * 64 + i * 16 + ln) * 32 + quad * 8];
        for (int j = 0; j < 4; j++)
            bfr[j] = *(const bf16x8*)&Bs[(wn * 64 + j * 16 + ln) * 32 + quad * 8];
        for (int i = 0; i < 4; i++)
            for (int j = 0; j < 4; j++)
                acc[i][j] = __builtin_amdgcn_mfma_f32_16x16x32_bf16(af[i], bfr[j], acc[i][j], 0, 0, 0);
        __syncthreads();
    }

    // epilogue: C/D layout col=lane&15, row=quad*4+r
    ushort* yb = y + (size_t)(b * NL + l) * NS * NDO;
    for (int j = 0; j < 4; j++) {
        int col = n0 + wn * 64 + j * 16 + ln;
        float bv = bias[l * NDO + col];
        for (int i = 0; i < 4; i++) {
            int rbase = m0 + wm * 64 + i * 16 + quad * 4;
            for (int r = 0; r < 4; r++) {
                yb[(size_t)(rbase + r) * NDO + col] = f2bf(acc[i][j][r] + bv);
            }
        }
    }
}

__device__ __forceinline__ void accum4(float4& a, uint2 v) {
    a.x += bf2f(v.x & 0xffffu);
    a.y += bf2f(v.x >> 16);
    a.z += bf2f(v.y & 0xffffu);
    a.w += bf2f(v.y >> 16);
}

// ---- gather: one wave per (b,t); indices pre-loaded lane-parallel, shfl-broadcast;
// 4-way unroll with independent accumulators -> 4+ outstanding y-row loads ----
__global__ __launch_bounds__(256) void gather_kernel(
    const ushort* __restrict__ y,
    const int* __restrict__ counts, const int* __restrict__ offsets,
    const int* __restrict__ sorted, float* __restrict__ out) {
    int g = blockIdx.x * 4 + (threadIdx.x >> 6);     // (b,t) id, < NB*NS
    int lane = threadIdx.x & 63;
    int b = g >> 11;                                  // NS = 2048
    int t = g & (NS - 1);

    int n = counts[b * NS + t];
    int off = offsets[b * NS + t];
    const int* ridx = sorted + (size_t)b * NE + off;

    float4 a0 = {0.f, 0.f, 0.f, 0.f};
    float4 a1 = {0.f, 0.f, 0.f, 0.f};
    float4 a2 = {0.f, 0.f, 0.f, 0.f};
    float4 a3 = {0.f, 0.f, 0.f, 0.f};

    for (int base = 0; base < n; base += 64) {
        int m = n - base;
        if (m > 64) m = 64;
        int my = (lane < m) ? ridx[base + lane] : 0;  // one vector load for up to 64 indices
        int k = 0;
        for (; k + 4 <= m; k += 4) {
            int i0 = __shfl(my, k);
            int i1 = __shfl(my, k + 1);
            int i2 = __shfl(my, k + 2);
            int i3 = __shfl(my, k + 3);
            uint2 v0 = ((const uint2*)(y + (size_t)i0 * NDO))[lane];
            uint2 v1 = ((const uint2*)(y + (size_t)i1 * NDO))[lane];
            uint2 v2 = ((const uint2*)(y + (size_t)i2 * NDO))[lane];
            uint2 v3 = ((const uint2*)(y + (size_t)i3 * NDO))[lane];
            accum4(a0, v0);
            accum4(a1, v1);
            accum4(a2, v2);
            accum4(a3, v3);
        }
        for (; k < m; k++) {
            int i0 = __shfl(my, k);
            uint2 v0 = ((const uint2*)(y + (size_t)i0 * NDO))[lane];
            accum4(a0, v0);
        }
    }

    float4 r;
    r.x = fmaxf(a0.x + a1.x + a2.x + a3.x, 0.f);
    r.y = fmaxf(a0.y + a1.y + a2.y + a3.y, 0.f);
    r.z = fmaxf(a0.z + a1.z + a2.z + a3.z, 0.f);
    r.w = fmaxf(a0.w + a1.w + a2.w + a3.w, 0.f);
    ((float4*)(out + (size_t)(b * NS + t) * NDO))[lane] = r;
}

extern "C" void kernel_launch(void* const* d_in, const int* in_sizes, int n_in,
                              void* d_out, int out_size, void* d_ws, size_t ws_size,
                              hipStream_t stream) {
    const float* x    = (const float*)d_in[0];
    const int*   esrc = (const int*)d_in[1];
    const int*   etgt = (const int*)d_in[2];
    const int*   elab = (const int*)d_in[3];
    const float* W    = (const float*)d_in[4];
    const float* bias = (const float*)d_in[5];
    float* out = (float*)d_out;

    char* ws = (char*)d_ws;
    // workspace layout (all 4KB-aligned offsets)
    ushort* xb     = (ushort*)(ws);                    //  8 MB: x bf16
    ushort* wt     = (ushort*)(ws + 8388608);          //  1 MB: W^T bf16
    ushort* y      = (ushort*)(ws + 9437184);          // 64 MB: y bf16
    int*    counts = (int*)(ws + 76546048);            // 64 KB
    int*    offs   = (int*)(ws + 76611584);            // 64 KB
    int*    cursor = (int*)(ws + 76677120);            // 64 KB
    int*    sorted = (int*)(ws + 76742656);            //  1 MB

    hipMemsetAsync(counts, 0, NB * NS * sizeof(int), stream);

    convert_x_kernel<<<4096, 256, 0, stream>>>(x, xb);          // NB*NS*ND/4/256
    convert_wt_kernel<<<2048, 256, 0, stream>>>(W, wt);         // NL*NDO*ND/256
    hist_kernel<<<1024, 256, 0, stream>>>(etgt, counts);        // NB*NE/256
    scan_kernel<<<NB, 256, 0, stream>>>(counts, offs, cursor);
    place_kernel<<<1024, 256, 0, stream>>>(etgt, esrc, elab, cursor, sorted);
    gemm_kernel<<<dim3(2, 16, 64), 256, 0, stream>>>(xb, wt, bias, y);
    gather_kernel<<<4096, 256, 0, stream>>>(y, counts, offs, sorted, out);
}